// Round 5
// baseline (147.999 us; speedup 1.0000x reference)
//
#include <hip/hip_runtime.h>
#include <float.h>
#include <stdint.h>

// CorrLoss via bf16 MFMA, symmetric tiles, LDS-free single-wave blocks:
//   k0: cast feat fp32 -> bf16 (RNE); init monotone-key min/max arrays + counter
//   k1: 2080 upper-tri 64x64 tiles, ONE WAVE per block. MFMA fragments loaded
//       directly global->VGPR (16B/lane, coalesced 16x64B) -- no LDS, no
//       barriers, no vmcnt(0) drain; depth-2 fragment prefetch. Masked per-row
//       min/max (direct + transposed) folded via device-scope atomicMin/Max on
//       order-preserving uint keys. Last block folds 32KB of keys -> out[0].

#define N_ROWS 4096
#define D_K    512
#define BT     64
#define NTB    (N_ROWS / BT)           // 64
#define NTILES (NTB * (NTB + 1) / 2)   // 2080
#define MARGIN 40.0f

typedef __bf16 bf16_t;
typedef bf16_t bf16x8 __attribute__((ext_vector_type(8)));
typedef float  floatx4 __attribute__((ext_vector_type(4)));
typedef unsigned short ushort_t;
typedef ushort_t ushortx8 __attribute__((ext_vector_type(8)));

__device__ __forceinline__ ushort_t f2bf_rne(float x) {
    uint32_t u = __builtin_bit_cast(uint32_t, x);
    return (ushort_t)((u + 0x7FFFu + ((u >> 16) & 1u)) >> 16);
}

// order-preserving float <-> uint key (larger float => larger key)
__device__ __forceinline__ unsigned fkey(float f) {
    unsigned u = __builtin_bit_cast(unsigned, f);
    return (u & 0x80000000u) ? ~u : (u | 0x80000000u);
}
__device__ __forceinline__ float funkey(unsigned k) {
    unsigned u = (k & 0x80000000u) ? (k & 0x7FFFFFFFu) : ~k;
    return __builtin_bit_cast(float, u);
}

__global__ __launch_bounds__(256) void cast_kernel(
    const float* __restrict__ f, ushort_t* __restrict__ o,
    unsigned* __restrict__ ap_key, unsigned* __restrict__ an_key,
    int* __restrict__ counter)
{
    const int gid = blockIdx.x * 256 + threadIdx.x;
    if (gid < N_ROWS) { ap_key[gid] = 0xFFFFFFFFu; an_key[gid] = 0u; }
    if (gid == 0) *counter = 0;

    const int i = gid * 8;
    const float4 v0 = *(const float4*)(f + i);
    const float4 v1 = *(const float4*)(f + i + 4);
    ushortx8 r;
    r[0] = f2bf_rne(v0.x); r[1] = f2bf_rne(v0.y);
    r[2] = f2bf_rne(v0.z); r[3] = f2bf_rne(v0.w);
    r[4] = f2bf_rne(v1.x); r[5] = f2bf_rne(v1.y);
    r[6] = f2bf_rne(v1.z); r[7] = f2bf_rne(v1.w);
    *(ushortx8*)(o + i) = r;
}

__global__ __launch_bounds__(64) void gram_mfma_kernel(
    const ushort_t* __restrict__ fb, const int* __restrict__ tgt,
    unsigned* __restrict__ ap_key, unsigned* __restrict__ an_key,
    int* __restrict__ counter, float* __restrict__ out)
{
    // flat block id -> upper-tri (bi, bj), row-major
    int bi = 0, rem = blockIdx.x;
    while (rem >= NTB - bi) { rem -= NTB - bi; ++bi; }
    const int bj = bi + rem;

    const int lane = threadIdx.x;    // single wave
    const int lr   = lane & 15;      // fragment row (A/B) / col (C/D)
    const int lg   = lane >> 4;      // k-group (A/B) / row-quad (C/D)
    const int i0   = bi * BT;
    const int j0   = bj * BT;

    // A-frag for 16x16x32: lane holds A[m=lr][k = lg*8 + 0..7] -> 16B global
    const bf16_t* pA = (const bf16_t*)fb + (size_t)(i0 + lr) * D_K + lg * 8;
    const bf16_t* pB = (const bf16_t*)fb + (size_t)(j0 + lr) * D_K + lg * 8;

    floatx4 acc[4][4];
#pragma unroll
    for (int a = 0; a < 4; ++a)
#pragma unroll
        for (int b = 0; b < 4; ++b) acc[a][b] = (floatx4)0.0f;

    bf16x8 A0[4], B0[4], A1[4], B1[4];
#pragma unroll
    for (int g = 0; g < 4; ++g) {
        A0[g] = *(const bf16x8*)(pA + (size_t)g * 16 * D_K);
        B0[g] = *(const bf16x8*)(pB + (size_t)g * 16 * D_K);
        A1[g] = *(const bf16x8*)(pA + (size_t)g * 16 * D_K + 32);
        B1[g] = *(const bf16x8*)(pB + (size_t)g * 16 * D_K + 32);
    }

#define MFMA16(Af, Bf)                                                    \
    do {                                                                  \
        _Pragma("unroll")                                                 \
        for (int rg = 0; rg < 4; ++rg)                                    \
            _Pragma("unroll")                                             \
            for (int cg = 0; cg < 4; ++cg)                                \
                acc[rg][cg] = __builtin_amdgcn_mfma_f32_16x16x32_bf16(    \
                    Af[rg], Bf[cg], acc[rg][cg], 0, 0, 0);                \
    } while (0)

    // depth-2 pipelined K-loop: 16 steps of BK=32, no barriers anywhere
    for (int it = 0; it < 16; it += 2) {
        MFMA16(A0, B0);
        const int kp0 = (it + 2) * 32;
        if (kp0 < D_K) {
#pragma unroll
            for (int g = 0; g < 4; ++g) {
                A0[g] = *(const bf16x8*)(pA + (size_t)g * 16 * D_K + kp0);
                B0[g] = *(const bf16x8*)(pB + (size_t)g * 16 * D_K + kp0);
            }
        }
        MFMA16(A1, B1);
        const int kp1 = (it + 3) * 32;
        if (kp1 < D_K) {
#pragma unroll
            for (int g = 0; g < 4; ++g) {
                A1[g] = *(const bf16x8*)(pA + (size_t)g * 16 * D_K + kp1);
                B1[g] = *(const bf16x8*)(pB + (size_t)g * 16 * D_K + kp1);
            }
        }
    }

    // ---- epilogue: C/D frag layout: col = lr, row = lg*4 + reg ----
    int4 ti4[4];
#pragma unroll
    for (int rg = 0; rg < 4; ++rg)
        ti4[rg] = *(const int4*)&tgt[i0 + rg * 16 + lg * 4];
    int tj[4];
#pragma unroll
    for (int cg = 0; cg < 4; ++cg) tj[cg] = tgt[j0 + cg * 16 + lr];

    float apT[4], anT[4];
#pragma unroll
    for (int cg = 0; cg < 4; ++cg) { apT[cg] = FLT_MAX; anT[cg] = -FLT_MAX; }

#pragma unroll
    for (int rg = 0; rg < 4; ++rg) {
        const int tiv[4] = {ti4[rg].x, ti4[rg].y, ti4[rg].z, ti4[rg].w};
#pragma unroll
        for (int r = 0; r < 4; ++r) {
            const int ti = tiv[r];
            float vap = FLT_MAX, van = -FLT_MAX;
#pragma unroll
            for (int cg = 0; cg < 4; ++cg) {
                const float v = acc[rg][cg][r];
                if (ti == tj[cg]) { vap = fminf(vap, v); apT[cg] = fminf(apT[cg], v); }
                else              { van = fmaxf(van, v); anT[cg] = fmaxf(anT[cg], v); }
            }
            // direct: reduce over 16 cols (lanes differing in lr bits 0..3)
#pragma unroll
            for (int m = 1; m < 16; m <<= 1) {
                vap = fminf(vap, __shfl_xor(vap, m));
                van = fmaxf(van, __shfl_xor(van, m));
            }
            if (lr == 0) {
                atomicMin(&ap_key[i0 + rg * 16 + lg * 4 + r], fkey(vap));
                atomicMax(&an_key[i0 + rg * 16 + lg * 4 + r], fkey(van));
            }
        }
    }
    if (bi != bj) {
        // transposed: reduce over the 4 lane-groups (rows already folded in-lane)
#pragma unroll
        for (int cg = 0; cg < 4; ++cg) {
            float vap = apT[cg], van = anT[cg];
            vap = fminf(vap, __shfl_xor(vap, 16)); van = fmaxf(van, __shfl_xor(van, 16));
            vap = fminf(vap, __shfl_xor(vap, 32)); van = fmaxf(van, __shfl_xor(van, 32));
            if (lg == 0) {
                atomicMin(&ap_key[j0 + cg * 16 + lr], fkey(vap));
                atomicMax(&an_key[j0 + cg * 16 + lr], fkey(van));
            }
        }
    }

    // ---- last-block fold ----
    __threadfence();
    int last = 0;
    if (lane == 0) last = (atomicAdd(counter, 1) == NTILES - 1) ? 1 : 0;
    last = __shfl(last, 0);
    if (!last) return;
    __threadfence();

    float local = 0.0f;
#pragma unroll 4
    for (int r = lane; r < N_ROWS; r += 64) {
        const float ap = funkey(ap_key[r]);
        const float an = funkey(an_key[r]);
        const float v = an - ap + MARGIN;
        local += (v > 0.0f) ? v : 0.0f;
    }
#pragma unroll
    for (int m = 32; m >= 1; m >>= 1) local += __shfl_down(local, m);
    if (lane == 0) out[0] = local * (1.0f / N_ROWS);
}

extern "C" void kernel_launch(void* const* d_in, const int* in_sizes, int n_in,
                              void* d_out, int out_size, void* d_ws, size_t ws_size,
                              hipStream_t stream)
{
    const float* feat = (const float*)d_in[0];
    const int*   tgt  = (const int*)d_in[1];

    ushort_t* fb      = (ushort_t*)d_ws;                        // 4 MB bf16 feat
    unsigned* ap_key  = (unsigned*)(fb + (size_t)N_ROWS * D_K); // 16 KB
    unsigned* an_key  = ap_key + N_ROWS;                        // 16 KB
    int*      counter = (int*)(an_key + N_ROWS);

    cast_kernel<<<(N_ROWS * D_K) / (256 * 8), 256, 0, stream>>>(
        feat, fb, ap_key, an_key, counter);
    gram_mfma_kernel<<<NTILES, 64, 0, stream>>>(
        fb, tgt, ap_key, an_key, counter, (float*)d_out);
}